// Round 19
// baseline (92.203 us; speedup 1.0000x reference)
//
#include <hip/hip_runtime.h>
#include <math.h>

#define BSZ   16
#define LSEQ  1024
#define TGT   256
#define HID   512
#define TV    2000
#define VOC   3000
#define SRC   2048
#define NKE   1280     // WkE rows: 2 j-halves x 640 (512 d + sentinel + bias + pad)
#define JOFF  640
#define CTILE 256      // combine entry tile
#define SCALE 0.044194173824159216f   // 1/sqrt(512)

typedef unsigned short u16;
typedef __attribute__((ext_vector_type(8))) short bf16x8;
typedef __attribute__((ext_vector_type(4))) float f32x4;

__device__ __forceinline__ u16 f2bf(float x) {
    unsigned u = __float_as_uint(x);
    u += 0x7FFFu + ((u >> 16) & 1u);
    return (u16)(u >> 16);
}
__device__ __forceinline__ float bf2f(u16 x) {
    return __uint_as_float((unsigned)x << 16);
}

static __device__ __forceinline__ float gelu_exact(float x) {
    return 0.5f * x * (1.0f + erff(x * 0.70710678118654752f));
}

// async 16B global -> LDS (wave-uniform LDS base + lane*16)
__device__ __forceinline__ void gload16(const u16* g, u16* l) {
    __builtin_amdgcn_global_load_lds(
        (const __attribute__((address_space(1))) unsigned int*)g,
        (__attribute__((address_space(3))) unsigned int*)l,
        16, 0, 0);
}

__device__ __forceinline__ void cast8_body(const float4* __restrict__ in,
                                           int4* __restrict__ out, int i) {
    float4 x = in[2 * i], y = in[2 * i + 1];
    unsigned p0 = (unsigned)f2bf(x.x) | ((unsigned)f2bf(x.y) << 16);
    unsigned p1 = (unsigned)f2bf(x.z) | ((unsigned)f2bf(x.w) << 16);
    unsigned p2 = (unsigned)f2bf(y.x) | ((unsigned)f2bf(y.y) << 16);
    unsigned p3 = (unsigned)f2bf(y.z) | ((unsigned)f2bf(y.w) << 16);
    out[i] = make_int4(p0, p1, p2, p3);
}

// ---------------- d1: prep_a — featb cast | Wq^T | WkE | rowsum zero | buckets ----------------
// blocks: [0,1024) feat cast | [1024,1280) Wq^T | [1280,1600) WkE | 1600 rowsum | [1601,1617) buckets
__global__ __launch_bounds__(256) void prep_a(
    const float* __restrict__ feature, const float* __restrict__ Wq,
    const float* __restrict__ Wk, const float* __restrict__ sentinel,
    const float* __restrict__ bk, const int* __restrict__ ce,
    int4* __restrict__ featb, u16* __restrict__ wqT, u16* __restrict__ wkE,
    float* __restrict__ rowsum, int* __restrict__ boff, u16* __restrict__ bucket)
{
    __shared__ float t[32][33];
    __shared__ int cnt[VOC];
    __shared__ int part[256];
    const int id = blockIdx.x;
    const int tid = threadIdx.x;
    if (id < 1024) {
        cast8_body((const float4*)feature, featb, id * 256 + tid);
    } else if (id < 1280) {
        int id2 = id - 1024;
        int bx = (id2 & 15) * 32, by = (id2 >> 4) * 32;
        const int tx = tid & 31, ty = tid >> 5;
        #pragma unroll
        for (int k = 0; k < 4; ++k)
            t[ty + 8 * k][tx] = Wq[(size_t)(by + ty + 8 * k) * 512 + bx + tx];
        __syncthreads();
        #pragma unroll
        for (int k = 0; k < 4; ++k)
            wqT[(size_t)(bx + ty + 8 * k) * 512 + by + tx] = f2bf(t[tx][ty + 8 * k]);
    } else if (id < 1600) {
        const int rr = (id - 1280) * 4 + (tid >> 6);   // 0..1279
        const int c = (tid & 63) * 8;
        const int j = rr >= JOFF;
        const int dd = rr - j * JOFF;
        u16* dst = wkE + (size_t)rr * HID + c;
        if (dd < 512) {
            const float* src = Wk + (size_t)dd * 1024 + j * 512 + c;
            #pragma unroll
            for (int k = 0; k < 8; ++k) dst[k] = f2bf(src[k]);
        } else if (dd == 512) {
            #pragma unroll
            for (int k = 0; k < 8; ++k) dst[k] = f2bf(sentinel[c + k]);
        } else if (dd == 513) {
            #pragma unroll
            for (int k = 0; k < 8; ++k) dst[k] = f2bf(bk[j * 512 + c + k]);
        } else {
            #pragma unroll
            for (int k = 0; k < 8; ++k) dst[k] = 0;
        }
    } else if (id == 1600) {
        float4* rz = (float4*)rowsum;
        for (int i = tid; i < 1024; i += 256) rz[i] = make_float4(0.f, 0.f, 0.f, 0.f);
    } else {
        // bucket build: one block per batch
        const int b = id - 1601;
        const int* ceb = ce + (size_t)b * SRC;
        for (int v = tid; v < VOC; v += 256) cnt[v] = 0;
        __syncthreads();
        for (int s = tid; s < SRC; s += 256) atomicAdd(&cnt[ceb[s]], 1);
        __syncthreads();
        const int base = tid * 12;
        int lc[12];
        int tot = 0;
        #pragma unroll
        for (int k = 0; k < 12; ++k) {
            int v = base + k;
            lc[k] = (v < VOC) ? cnt[v] : 0;
            tot += lc[k];
        }
        part[tid] = tot;
        __syncthreads();
        for (int d = 1; d < 256; d <<= 1) {
            int val = (tid >= d) ? part[tid - d] : 0;
            __syncthreads();
            part[tid] += val;
            __syncthreads();
        }
        int run = part[tid] - tot;
        int* boffb = boff + b * 3008;
        #pragma unroll
        for (int k = 0; k < 12; ++k) {
            int v = base + k;
            if (v < VOC) { boffb[v] = run; cnt[v] = run; run += lc[k]; }
        }
        if (tid == 0) boffb[VOC] = SRC;
        __syncthreads();
        for (int s = tid; s < SRC; s += 256) {
            int idv = ceb[s];
            int jl = (s & 1) * 1024 + (s >> 1);
            int pos = atomicAdd(&cnt[idv], 1);
            bucket[(size_t)b * SRC + pos] = (u16)jl;
        }
    }
}

// ---------------- d2: query GEMM (512 blocks) + memb cast (4096 blocks) ----------------
__global__ __launch_bounds__(256) void k_query(
    const u16* __restrict__ feat, const u16* __restrict__ wqT,
    const float* __restrict__ bq, u16* __restrict__ queryb,
    const float* __restrict__ memory_raw, int4* __restrict__ memb)
{
    __shared__ u16 sbuf[2 * 2048 * 2];   // As | Bs (16 KB)
    const int id = blockIdx.x;
    const int tid = threadIdx.x;
    if (id >= 512) {
        cast8_body((const float4*)memory_raw, memb, (id - 512) * 256 + tid);
        return;
    }
    u16* As = sbuf;
    u16* Bs = sbuf + 2 * 2048;
    const int lane = tid & 63;
    const int w = tid >> 6;
    const int wr = (w >> 1) * 32, wc = (w & 1) * 32;
    const int m0 = (id >> 3) * 64, n0 = (id & 7) * 64;

    const int srow = tid >> 2, scol = (tid & 3) * 8;
    const u16* gA = feat + (size_t)(m0 + srow) * HID + scol;
    const u16* gB = wqT + (size_t)(n0 + srow) * HID + scol;

    const int la = lane & 15, lb = lane >> 4;
    f32x4 acc[2][2] = {};

    gload16(gA, As + w * 512);
    gload16(gB, Bs + w * 512);

    int cur = 0;
    for (int k0 = 0; k0 < HID; k0 += 32) {
        __syncthreads();   // drains vmcnt(0) + barrier
        const u16* Asb = As + cur * 2048;
        const u16* Bsb = Bs + cur * 2048;
        bf16x8 af[2], bf[2];
        #pragma unroll
        for (int i = 0; i < 2; ++i)
            af[i] = *(const bf16x8*)(Asb + (wr + i * 16 + la) * 32 + lb * 8);
        #pragma unroll
        for (int j = 0; j < 2; ++j)
            bf[j] = *(const bf16x8*)(Bsb + (wc + j * 16 + la) * 32 + lb * 8);
        if (k0 + 32 < HID) {
            const int nb = cur ^ 1;
            gload16(gA + k0 + 32, As + nb * 2048 + w * 512);
            gload16(gB + k0 + 32, Bs + nb * 2048 + w * 512);
        }
        #pragma unroll
        for (int i = 0; i < 2; ++i)
            #pragma unroll
            for (int j = 0; j < 2; ++j)
                acc[i][j] = __builtin_amdgcn_mfma_f32_16x16x32_bf16(af[i], bf[j], acc[i][j], 0, 0, 0);
        cur ^= 1;
    }

    const int r_l = (lane >> 4) * 4, c_l = lane & 15;
    #pragma unroll
    for (int j = 0; j < 2; ++j) {
        const int n = n0 + wc + j * 16 + c_l;
        const float bv = bq[n];
        #pragma unroll
        for (int i = 0; i < 2; ++i)
            #pragma unroll
            for (int r = 0; r < 4; ++r) {
                const int m = m0 + wr + i * 16 + r_l + r;
                queryb[(size_t)m * HID + n] = f2bf(gelu_exact(acc[i][j][r] + bv));
            }
    }
}

// ---------------- MFMA GEMM body (128x128, BK=32) for qk and atten ----------------
template<int EPI, int LDA, int LDB>
__device__ __forceinline__ void gemm_body(
    int m0, int n0, int z,
    const u16* __restrict__ Abase, const u16* __restrict__ Bbase,
    u16* __restrict__ outb,
    const int* __restrict__ ce, float* __restrict__ rowsum,
    u16* __restrict__ As, u16* __restrict__ Bs)   // each 2*4096 u16
{
    const int tid = threadIdx.x;
    const int lane = tid & 63;
    const int w = tid >> 6;
    const int wr = (w >> 1) * 64, wc = (w & 1) * 64;

    const u16* Ag = Abase;
    const u16* Bg = Bbase;
    if (EPI == 2) {
        Ag = Abase + (size_t)(z >> 1) * LSEQ * HID;
        Bg = Bbase + (size_t)(z >> 1) * TGT * NKE + (size_t)(z & 1) * JOFF;
    }

    const int chunkrow = lane >> 2;
    const int colc = (lane & 3) * 8;
    const int c0 = w * 2, c1 = c0 + 1;
    const u16* gA0 = Ag + (size_t)(m0 + c0 * 16 + chunkrow) * LDA + colc;
    const u16* gA1 = Ag + (size_t)(m0 + c1 * 16 + chunkrow) * LDA + colc;
    const u16* gB0 = Bg + (size_t)(n0 + c0 * 16 + chunkrow) * LDB + colc;
    const u16* gB1 = Bg + (size_t)(n0 + c1 * 16 + chunkrow) * LDB + colc;

    const int la = lane & 15, lb = lane >> 4;
    f32x4 acc[4][4] = {};

    gload16(gA0, As + c0 * 512);
    gload16(gA1, As + c1 * 512);
    gload16(gB0, Bs + c0 * 512);
    gload16(gB1, Bs + c1 * 512);

    int cur = 0;
    for (int k0 = 0; k0 < HID; k0 += 32) {
        __syncthreads();
        const u16* Asb = As + cur * 4096;
        const u16* Bsb = Bs + cur * 4096;
        bf16x8 af[4], bfv[4];
        #pragma unroll
        for (int i = 0; i < 4; ++i)
            af[i] = *(const bf16x8*)(Asb + (wr + i * 16 + la) * 32 + lb * 8);
        #pragma unroll
        for (int j = 0; j < 4; ++j)
            bfv[j] = *(const bf16x8*)(Bsb + (wc + j * 16 + la) * 32 + lb * 8);
        if (k0 + 32 < HID) {
            const int nb = cur ^ 1;
            u16* An = As + nb * 4096;
            u16* Bn = Bs + nb * 4096;
            gload16(gA0 + k0 + 32, An + c0 * 512);
            gload16(gA1 + k0 + 32, An + c1 * 512);
            gload16(gB0 + k0 + 32, Bn + c0 * 512);
            gload16(gB1 + k0 + 32, Bn + c1 * 512);
        }
        #pragma unroll
        for (int i = 0; i < 4; ++i)
            #pragma unroll
            for (int j = 0; j < 4; ++j)
                acc[i][j] = __builtin_amdgcn_mfma_f32_16x16x32_bf16(af[i], bfv[j], acc[i][j], 0, 0, 0);
        cur ^= 1;
    }

    const int r_l = (lane >> 4) * 4, c_l = lane & 15;
    if (EPI == 3) {
        #pragma unroll
        for (int j = 0; j < 4; ++j) {
            const int n = n0 + wc + j * 16 + c_l;
            #pragma unroll
            for (int i = 0; i < 4; ++i)
                #pragma unroll
                for (int r = 0; r < 4; ++r) {
                    const int m = m0 + wr + i * 16 + r_l + r;
                    outb[(size_t)m * NKE + n] = f2bf(acc[i][j][r]);
                }
        }
    } else {
        const int b = z >> 1, jj = z & 1;
        float biasc[4];
        #pragma unroll
        for (int j = 0; j < 4; ++j) {
            const int n = n0 + wc + j * 16 + c_l;   // t
            biasc[j] = bf2f(Bbase[(size_t)(b * TGT + n) * NKE + jj * JOFF + 513]);
        }
        const int* ceb = ce + (size_t)b * SRC;
        float csum[4] = {0.f, 0.f, 0.f, 0.f};
        #pragma unroll
        for (int i = 0; i < 4; ++i)
            #pragma unroll
            for (int r = 0; r < 4; ++r) {
                const int m = m0 + wr + i * 16 + r_l + r;      // l
                const int cm = ceb[2 * m + jj];
                const size_t rowbase = ((size_t)b * SRC + jj * 1024 + m) * TGT;
                #pragma unroll
                for (int j = 0; j < 4; ++j) {
                    float ev = (cm == 0) ? 0.f
                             : __expf((acc[i][j][r] + biasc[j]) * SCALE);
                    outb[rowbase + n0 + wc + j * 16 + c_l] = f2bf(ev);
                    csum[j] += ev;
                }
            }
        #pragma unroll
        for (int j = 0; j < 4; ++j) {
            csum[j] += __shfl_xor(csum[j], 16, 64);
            csum[j] += __shfl_xor(csum[j], 32, 64);
        }
        const int jsel = lane >> 4;
        float myv = (jsel == 0) ? csum[0] : (jsel == 1) ? csum[1]
                  : (jsel == 2) ? csum[2] : csum[3];
        atomicAdd(&rowsum[b * TGT + n0 + wc + jsel * 16 + c_l], myv);
    }
}

// ---------------- d3: qk GEMM (320) + logits LSE (1024 filler) ----------------
__global__ __launch_bounds__(256) void k_qk(
    const u16* __restrict__ queryb, const u16* __restrict__ wkE,
    u16* __restrict__ qkb,
    const float* __restrict__ logits, float* __restrict__ lse)
{
    __shared__ u16 sbuf[4 * 4096];   // 32 KB GEMM As|Bs
    const int id = blockIdx.x;
    const int tid = threadIdx.x;
    if (id < 320) {
        gemm_body<3, 512, 512>((id / 10) * 128, (id % 10) * 128, 0,
                               queryb, wkE, qkb, nullptr, nullptr,
                               sbuf, sbuf + 2 * 4096);
    } else {
        // logits LSE: 4 rows per block, one wave per row (TV = 500 float4)
        const int row = (id - 320) * 4 + (tid >> 6);
        const int lane = tid & 63;
        const float4* lrow4 = (const float4*)(logits + (size_t)row * TV);
        float4 v4[8];
        float m = -INFINITY;
        #pragma unroll
        for (int k = 0; k < 8; ++k) {
            int idx = lane + 64 * k;
            if (idx < 500) {
                v4[k] = lrow4[idx];
                m = fmaxf(m, fmaxf(fmaxf(v4[k].x, v4[k].y), fmaxf(v4[k].z, v4[k].w)));
            } else {
                v4[k] = make_float4(-INFINITY, -INFINITY, -INFINITY, -INFINITY);
            }
        }
        #pragma unroll
        for (int o = 32; o > 0; o >>= 1) m = fmaxf(m, __shfl_xor(m, o, 64));
        float s = 0.f;
        #pragma unroll
        for (int k = 0; k < 8; ++k)
            s += __expf(v4[k].x - m) + __expf(v4[k].y - m)
               + __expf(v4[k].z - m) + __expf(v4[k].w - m);
        #pragma unroll
        for (int o = 32; o > 0; o >>= 1) s += __shfl_xor(s, o, 64);
        if (lane == 0) lse[row] = m + __logf(s);
    }
}

// ---------------- d4: atten — pure, 512 blocks, XCD-grouped per (b,jj) ----------------
__global__ __launch_bounds__(256) void k_atten(
    const u16* __restrict__ memb, const u16* __restrict__ qkb,
    const int* __restrict__ ce, float* __restrict__ rowsum,
    u16* __restrict__ etb)
{
    __shared__ u16 As[2 * 4096];
    __shared__ u16 Bs[2 * 4096];
    const int i = blockIdx.x;
    const int xcd = i & 7, slot = i >> 3;        // slot in [0,64)
    const int bjj = xcd + 8 * (slot >> 4);       // [0,32) = b*2+jj
    const int inner = slot & 15;                 // 8 l-tiles x 2 t-tiles
    gemm_body<2, 512, NKE>((inner >> 1) * 128, (inner & 1) * 128, bjj,
                           memb, qkb, etb, ce, rowsum, As, Bs);
}

// ---------------- d5: combine-v6 — two-phase gather. 6144 blocks = 16 b x 32 tc x 12 vs ----------------
__global__ __launch_bounds__(256) void combine(
    const u16* __restrict__ etb, const u16* __restrict__ bucket,
    const int* __restrict__ boff, const u16* __restrict__ qkb,
    const float* __restrict__ rowsum, const float* __restrict__ lse,
    const float* __restrict__ out_logits, float* __restrict__ out)
{
    __shared__ float part[CTILE][9];   // 9 KB entry partials (pad 9: conflict-free)
    __shared__ float acc[8][256];      // 8 KB [t-local][v-local]
    __shared__ float rcInv[8], rcGZ[8], rcEdl[8], rcDl[8];
    const int i = blockIdx.x;
    const int xcd = i & 7, slot = i >> 3;      // slot in [0,768)
    const int b = xcd + 8 * (slot / 384);      // all 384 blocks of b on one XCD
    const int inner = slot % 384;
    const int tc = inner / 12, vs = inner % 12;
    const int t0 = tc * 8;
    const int vbase = vs * 256;
    const int tid = threadIdx.x;
    const float EPSF = 1.1920929e-07f;

    if (tid < 8) {
        const int bt = b * TGT + t0 + tid;
        const float sent_v = bf2f(qkb[(size_t)bt * NKE + 512]) * SCALE;
        const float se = __expf(sent_v);
        const float sm = rowsum[bt] + se;
        const float inv = 1.0f / sm;
        const float g = sent_v - __logf(sm);
        const float eg = se * inv;
        const float dl = __logf(1.0f - eg + EPSF) - log1pf(-eg + EPSF);
        rcInv[tid] = inv;
        rcGZ[tid] = g - lse[bt];
        rcEdl[tid] = __expf(dl);
        rcDl[tid] = dl;
    }

    const int* boffb = boff + b * 3008;
    const u16* bukb = bucket + (size_t)b * SRC;
    const u16* etbb = etb + (size_t)b * SRC * TGT;

    const int vend = (vbase + 256 < VOC) ? vbase + 256 : VOC;
    const int e_lo = boffb[vbase];
    const int cnt = boffb[vend] - e_lo;
    const int v = vbase + tid;
    const int i0 = (v < VOC) ? boffb[v] - e_lo : 0;
    const int i1 = (v < VOC) ? boffb[v + 1] - e_lo : 0;

    float a[8] = {0.f, 0.f, 0.f, 0.f, 0.f, 0.f, 0.f, 0.f};
    for (int ts = 0; ts < cnt; ts += CTILE) {
        const int n = (cnt - ts < CTILE) ? cnt - ts : CTILE;
        __syncthreads();   // part[] free for reuse
        for (int e = tid; e < n; e += 256) {
            const int s = bukb[e_lo + ts + e];
            int4 u = *(const int4*)(etbb + (size_t)s * TGT + t0);
            part[e][0] = bf2f((u16)(u.x & 0xffff));
            part[e][1] = bf2f((u16)((unsigned)u.x >> 16));
            part[e][2] = bf2f((u16)(u.y & 0xffff));
            part[e][3] = bf2f((u16)((unsigned)u.y >> 16));
            part[e][4] = bf2f((u16)(u.z & 0xffff));
            part[e][5] = bf2f((u16)((unsigned)u.z >> 16));
            part[e][6] = bf2f((u16)(u.w & 0xffff));
            part[e][7] = bf2f((u16)((unsigned)u.w >> 16));
        }
        __syncthreads();
        int lo = i0 - ts; if (lo < 0) lo = 0;
        int hi = i1 - ts; if (hi > n) hi = n;
        for (int e = lo; e < hi; ++e) {
            #pragma unroll
            for (int k = 0; k < 8; ++k) a[k] += part[e][k];
        }
    }
    #pragma unroll
    for (int k = 0; k < 8; ++k) acc[k][tid] = a[k];
    __syncthreads();

    const int r = tid >> 5;
    const int vl0 = tid & 31;
    const int bt = b * TGT + t0 + r;
    const float inv = rcInv[r], gZ = rcGZ[r], edl = rcEdl[r], dlv = rcDl[r];
    const float* lrow = out_logits + (size_t)bt * TV;
    float* orow = out + (size_t)bt * VOC;
    #pragma unroll
    for (int kk = 0; kk < 8; ++kk) {
        const int vloc = vl0 + 32 * kk;
        const int vv = vbase + vloc;
        if (vv >= VOC) continue;
        float pv = acc[r][vloc] * inv + EPSF;
        float o;
        if (vv < TV) o = __logf(__expf(lrow[vv] + gZ) + pv * edl);
        else         o = __logf(pv) + dlv;
        orow[vv] = o;
    }
}

extern "C" void kernel_launch(void* const* d_in, const int* in_sizes, int n_in,
                              void* d_out, int out_size, void* d_ws, size_t ws_size,
                              hipStream_t stream) {
    const float* out_logits = (const float*)d_in[0];
    const float* feature    = (const float*)d_in[1];
    const float* memory_raw = (const float*)d_in[2];
    const int*   content_e  = (const int*)d_in[3];
    const float* Wq = (const float*)d_in[4];
    const float* bq = (const float*)d_in[5];
    const float* Wk = (const float*)d_in[6];
    const float* bk = (const float*)d_in[7];
    const float* sentinel = (const float*)d_in[8];
    float* out = (float*)d_out;

    u16* memb   = (u16*)d_ws;                             // 16384*512 bf16
    u16* featb  = memb   + (size_t)16384 * 512;           // 4096*512
    u16* wqT    = featb  + (size_t)4096 * 512;            // 512*512
    u16* wkE    = wqT    + (size_t)512 * 512;             // 1280*512
    u16* queryb = wkE    + (size_t)NKE * 512;             // 4096*512
    u16* qkb    = queryb + (size_t)4096 * 512;            // 4096*1280
    u16* etb    = qkb    + (size_t)4096 * NKE;            // 16*2048*256 bf16 E^T
    float* rowsum = (float*)(etb + (size_t)BSZ * SRC * TGT); // 4096 f32
    float* lse   = rowsum + 4096;                         // 4096 f32
    int* boff = (int*)(lse + 4096);                       // 16*3008 int
    u16* bucket = (u16*)(boff + 16 * 3008);               // 16*2048 u16

    prep_a<<<1617, 256, 0, stream>>>(feature, Wq, Wk, sentinel, bk, content_e,
                                     (int4*)featb, wqT, wkE, rowsum, boff, bucket);
    k_query<<<4608, 256, 0, stream>>>(featb, wqT, bq, queryb, memory_raw, (int4*)memb);
    k_qk<<<1344, 256, 0, stream>>>(queryb, wkE, qkb, out_logits, lse);
    k_atten<<<512, 256, 0, stream>>>(memb, qkb, content_e, rowsum, etb);
    combine<<<6144, 256, 0, stream>>>(etb, bucket, boff, qkb,
                                      rowsum, lse, out_logits, out);
}

// Round 20
// 89.660 us; speedup vs baseline: 1.0284x; 1.0284x over previous
//
#include <hip/hip_runtime.h>
#include <math.h>

#define BSZ   16
#define LSEQ  1024
#define TGT   256
#define HID   512
#define TV    2000
#define VOC   3000
#define SRC   2048
#define NKE   1280     // WkE rows: 2 j-halves x 640 (512 d + sentinel + bias + pad)
#define JOFF  640
#define CTILE 256      // combine entry tile
#define SCALE 0.044194173824159216f   // 1/sqrt(512)

typedef unsigned short u16;
typedef __attribute__((ext_vector_type(8))) short bf16x8;
typedef __attribute__((ext_vector_type(4))) float f32x4;

__device__ __forceinline__ u16 f2bf(float x) {
    unsigned u = __float_as_uint(x);
    u += 0x7FFFu + ((u >> 16) & 1u);
    return (u16)(u >> 16);
}
__device__ __forceinline__ float bf2f(u16 x) {
    return __uint_as_float((unsigned)x << 16);
}

static __device__ __forceinline__ float gelu_exact(float x) {
    return 0.5f * x * (1.0f + erff(x * 0.70710678118654752f));
}

// async 16B global -> LDS (wave-uniform LDS base + lane*16)
__device__ __forceinline__ void gload16(const u16* g, u16* l) {
    __builtin_amdgcn_global_load_lds(
        (const __attribute__((address_space(1))) unsigned int*)g,
        (__attribute__((address_space(3))) unsigned int*)l,
        16, 0, 0);
}

__device__ __forceinline__ void cast8_body(const float4* __restrict__ in,
                                           int4* __restrict__ out, int i) {
    float4 x = in[2 * i], y = in[2 * i + 1];
    unsigned p0 = (unsigned)f2bf(x.x) | ((unsigned)f2bf(x.y) << 16);
    unsigned p1 = (unsigned)f2bf(x.z) | ((unsigned)f2bf(x.w) << 16);
    unsigned p2 = (unsigned)f2bf(y.x) | ((unsigned)f2bf(y.y) << 16);
    unsigned p3 = (unsigned)f2bf(y.z) | ((unsigned)f2bf(y.w) << 16);
    out[i] = make_int4(p0, p1, p2, p3);
}

// ---------------- d1: prep_a — featb cast | Wq^T | WkE build | rowsum zero ----------------
// blocks: [0,1024) cast feature | [1024,1280) Wq^T | [1280,1600) WkE | 1600 rowsum=0
__global__ __launch_bounds__(256) void prep_a(
    const float* __restrict__ feature, const float* __restrict__ Wq,
    const float* __restrict__ Wk, const float* __restrict__ sentinel,
    const float* __restrict__ bk,
    int4* __restrict__ featb, u16* __restrict__ wqT, u16* __restrict__ wkE,
    float* __restrict__ rowsum)
{
    __shared__ float t[32][33];
    const int id = blockIdx.x;
    const int tid = threadIdx.x;
    if (id < 1024) {
        cast8_body((const float4*)feature, featb, id * 256 + tid);
    } else if (id < 1280) {
        int id2 = id - 1024;
        int bx = (id2 & 15) * 32, by = (id2 >> 4) * 32;
        const int tx = tid & 31, ty = tid >> 5;
        #pragma unroll
        for (int k = 0; k < 4; ++k)
            t[ty + 8 * k][tx] = Wq[(size_t)(by + ty + 8 * k) * 512 + bx + tx];
        __syncthreads();
        #pragma unroll
        for (int k = 0; k < 4; ++k)
            wqT[(size_t)(bx + ty + 8 * k) * 512 + by + tx] = f2bf(t[tx][ty + 8 * k]);
    } else if (id < 1600) {
        const int rr = (id - 1280) * 4 + (tid >> 6);   // 0..1279
        const int c = (tid & 63) * 8;
        const int j = rr >= JOFF;
        const int dd = rr - j * JOFF;
        u16* dst = wkE + (size_t)rr * HID + c;
        if (dd < 512) {
            const float* src = Wk + (size_t)dd * 1024 + j * 512 + c;
            #pragma unroll
            for (int k = 0; k < 8; ++k) dst[k] = f2bf(src[k]);
        } else if (dd == 512) {
            #pragma unroll
            for (int k = 0; k < 8; ++k) dst[k] = f2bf(sentinel[c + k]);
        } else if (dd == 513) {
            #pragma unroll
            for (int k = 0; k < 8; ++k) dst[k] = f2bf(bk[j * 512 + c + k]);
        } else {
            #pragma unroll
            for (int k = 0; k < 8; ++k) dst[k] = 0;
        }
    } else {
        float4* rz = (float4*)rowsum;
        for (int i = tid; i < 1024; i += 256) rz[i] = make_float4(0.f, 0.f, 0.f, 0.f);
    }
}

// ---------------- d2: query GEMM (512 blocks) + memb cast (4096 blocks) ----------------
__global__ __launch_bounds__(256) void k_query(
    const u16* __restrict__ feat, const u16* __restrict__ wqT,
    const float* __restrict__ bq, u16* __restrict__ queryb,
    const float* __restrict__ memory_raw, int4* __restrict__ memb)
{
    __shared__ u16 sbuf[2 * 2048 * 2];   // As | Bs (16 KB)
    const int id = blockIdx.x;
    const int tid = threadIdx.x;
    if (id >= 512) {
        cast8_body((const float4*)memory_raw, memb, (id - 512) * 256 + tid);
        return;
    }
    u16* As = sbuf;
    u16* Bs = sbuf + 2 * 2048;
    const int lane = tid & 63;
    const int w = tid >> 6;
    const int wr = (w >> 1) * 32, wc = (w & 1) * 32;
    const int m0 = (id >> 3) * 64, n0 = (id & 7) * 64;

    const int srow = tid >> 2, scol = (tid & 3) * 8;
    const u16* gA = feat + (size_t)(m0 + srow) * HID + scol;
    const u16* gB = wqT + (size_t)(n0 + srow) * HID + scol;

    const int la = lane & 15, lb = lane >> 4;
    f32x4 acc[2][2] = {};

    gload16(gA, As + w * 512);
    gload16(gB, Bs + w * 512);

    int cur = 0;
    for (int k0 = 0; k0 < HID; k0 += 32) {
        __syncthreads();   // drains vmcnt(0) + barrier
        const u16* Asb = As + cur * 2048;
        const u16* Bsb = Bs + cur * 2048;
        bf16x8 af[2], bf[2];
        #pragma unroll
        for (int i = 0; i < 2; ++i)
            af[i] = *(const bf16x8*)(Asb + (wr + i * 16 + la) * 32 + lb * 8);
        #pragma unroll
        for (int j = 0; j < 2; ++j)
            bf[j] = *(const bf16x8*)(Bsb + (wc + j * 16 + la) * 32 + lb * 8);
        if (k0 + 32 < HID) {
            const int nb = cur ^ 1;
            gload16(gA + k0 + 32, As + nb * 2048 + w * 512);
            gload16(gB + k0 + 32, Bs + nb * 2048 + w * 512);
        }
        #pragma unroll
        for (int i = 0; i < 2; ++i)
            #pragma unroll
            for (int j = 0; j < 2; ++j)
                acc[i][j] = __builtin_amdgcn_mfma_f32_16x16x32_bf16(af[i], bf[j], acc[i][j], 0, 0, 0);
        cur ^= 1;
    }

    const int r_l = (lane >> 4) * 4, c_l = lane & 15;
    #pragma unroll
    for (int j = 0; j < 2; ++j) {
        const int n = n0 + wc + j * 16 + c_l;
        const float bv = bq[n];
        #pragma unroll
        for (int i = 0; i < 2; ++i)
            #pragma unroll
            for (int r = 0; r < 4; ++r) {
                const int m = m0 + wr + i * 16 + r_l + r;
                queryb[(size_t)m * HID + n] = f2bf(gelu_exact(acc[i][j][r] + bv));
            }
    }
}

// ---------------- MFMA GEMM body (128x128, BK=32) for qk and atten ----------------
template<int EPI, int LDA, int LDB>
__device__ __forceinline__ void gemm_body(
    int m0, int n0, int z,
    const u16* __restrict__ Abase, const u16* __restrict__ Bbase,
    u16* __restrict__ outb,
    const int* __restrict__ ce, float* __restrict__ rowsum,
    u16* __restrict__ As, u16* __restrict__ Bs)   // each 2*4096 u16
{
    const int tid = threadIdx.x;
    const int lane = tid & 63;
    const int w = tid >> 6;
    const int wr = (w >> 1) * 64, wc = (w & 1) * 64;

    const u16* Ag = Abase;
    const u16* Bg = Bbase;
    if (EPI == 2) {
        Ag = Abase + (size_t)(z >> 1) * LSEQ * HID;
        Bg = Bbase + (size_t)(z >> 1) * TGT * NKE + (size_t)(z & 1) * JOFF;
    }

    const int chunkrow = lane >> 2;
    const int colc = (lane & 3) * 8;
    const int c0 = w * 2, c1 = c0 + 1;
    const u16* gA0 = Ag + (size_t)(m0 + c0 * 16 + chunkrow) * LDA + colc;
    const u16* gA1 = Ag + (size_t)(m0 + c1 * 16 + chunkrow) * LDA + colc;
    const u16* gB0 = Bg + (size_t)(n0 + c0 * 16 + chunkrow) * LDB + colc;
    const u16* gB1 = Bg + (size_t)(n0 + c1 * 16 + chunkrow) * LDB + colc;

    const int la = lane & 15, lb = lane >> 4;
    f32x4 acc[4][4] = {};

    gload16(gA0, As + c0 * 512);
    gload16(gA1, As + c1 * 512);
    gload16(gB0, Bs + c0 * 512);
    gload16(gB1, Bs + c1 * 512);

    int cur = 0;
    for (int k0 = 0; k0 < HID; k0 += 32) {
        __syncthreads();
        const u16* Asb = As + cur * 4096;
        const u16* Bsb = Bs + cur * 4096;
        bf16x8 af[4], bfv[4];
        #pragma unroll
        for (int i = 0; i < 4; ++i)
            af[i] = *(const bf16x8*)(Asb + (wr + i * 16 + la) * 32 + lb * 8);
        #pragma unroll
        for (int j = 0; j < 4; ++j)
            bfv[j] = *(const bf16x8*)(Bsb + (wc + j * 16 + la) * 32 + lb * 8);
        if (k0 + 32 < HID) {
            const int nb = cur ^ 1;
            u16* An = As + nb * 4096;
            u16* Bn = Bs + nb * 4096;
            gload16(gA0 + k0 + 32, An + c0 * 512);
            gload16(gA1 + k0 + 32, An + c1 * 512);
            gload16(gB0 + k0 + 32, Bn + c0 * 512);
            gload16(gB1 + k0 + 32, Bn + c1 * 512);
        }
        #pragma unroll
        for (int i = 0; i < 4; ++i)
            #pragma unroll
            for (int j = 0; j < 4; ++j)
                acc[i][j] = __builtin_amdgcn_mfma_f32_16x16x32_bf16(af[i], bfv[j], acc[i][j], 0, 0, 0);
        cur ^= 1;
    }

    const int r_l = (lane >> 4) * 4, c_l = lane & 15;
    if (EPI == 3) {
        #pragma unroll
        for (int j = 0; j < 4; ++j) {
            const int n = n0 + wc + j * 16 + c_l;
            #pragma unroll
            for (int i = 0; i < 4; ++i)
                #pragma unroll
                for (int r = 0; r < 4; ++r) {
                    const int m = m0 + wr + i * 16 + r_l + r;
                    outb[(size_t)m * NKE + n] = f2bf(acc[i][j][r]);
                }
        }
    } else {
        const int b = z >> 1, jj = z & 1;
        float biasc[4];
        #pragma unroll
        for (int j = 0; j < 4; ++j) {
            const int n = n0 + wc + j * 16 + c_l;   // t
            biasc[j] = bf2f(Bbase[(size_t)(b * TGT + n) * NKE + jj * JOFF + 513]);
        }
        const int* ceb = ce + (size_t)b * SRC;
        float csum[4] = {0.f, 0.f, 0.f, 0.f};
        #pragma unroll
        for (int i = 0; i < 4; ++i)
            #pragma unroll
            for (int r = 0; r < 4; ++r) {
                const int m = m0 + wr + i * 16 + r_l + r;      // l
                const int cm = ceb[2 * m + jj];
                const size_t rowbase = ((size_t)b * SRC + jj * 1024 + m) * TGT;
                #pragma unroll
                for (int j = 0; j < 4; ++j) {
                    float ev = (cm == 0) ? 0.f
                             : __expf((acc[i][j][r] + biasc[j]) * SCALE);
                    outb[rowbase + n0 + wc + j * 16 + c_l] = f2bf(ev);
                    csum[j] += ev;
                }
            }
        #pragma unroll
        for (int j = 0; j < 4; ++j) {
            csum[j] += __shfl_xor(csum[j], 16, 64);
            csum[j] += __shfl_xor(csum[j], 32, 64);
        }
        const int jsel = lane >> 4;
        float myv = (jsel == 0) ? csum[0] : (jsel == 1) ? csum[1]
                  : (jsel == 2) ? csum[2] : csum[3];
        atomicAdd(&rowsum[b * TGT + n0 + wc + jsel * 16 + c_l], myv);
    }
}

// ---------------- d3: qk GEMM (320) + logits LSE (1024) + bucket build (16) ----------------
__global__ __launch_bounds__(256) void k_qk(
    const u16* __restrict__ queryb, const u16* __restrict__ wkE,
    u16* __restrict__ qkb,
    const float* __restrict__ logits, float* __restrict__ lse,
    const int* __restrict__ ce, int* __restrict__ boff, u16* __restrict__ bucket)
{
    __shared__ u16 sbuf[4 * 4096];   // 32 KB: GEMM As|Bs, or bucket cnt|part overlay
    const int id = blockIdx.x;
    const int tid = threadIdx.x;
    if (id < 320) {
        gemm_body<3, 512, 512>((id / 10) * 128, (id % 10) * 128, 0,
                               queryb, wkE, qkb, nullptr, nullptr,
                               sbuf, sbuf + 2 * 4096);
    } else if (id < 1344) {
        // logits LSE: 4 rows per block, one wave per row (TV = 500 float4)
        const int row = (id - 320) * 4 + (tid >> 6);
        const int lane = tid & 63;
        const float4* lrow4 = (const float4*)(logits + (size_t)row * TV);
        float4 v4[8];
        float m = -INFINITY;
        #pragma unroll
        for (int k = 0; k < 8; ++k) {
            int idx = lane + 64 * k;
            if (idx < 500) {
                v4[k] = lrow4[idx];
                m = fmaxf(m, fmaxf(fmaxf(v4[k].x, v4[k].y), fmaxf(v4[k].z, v4[k].w)));
            } else {
                v4[k] = make_float4(-INFINITY, -INFINITY, -INFINITY, -INFINITY);
            }
        }
        #pragma unroll
        for (int o = 32; o > 0; o >>= 1) m = fmaxf(m, __shfl_xor(m, o, 64));
        float s = 0.f;
        #pragma unroll
        for (int k = 0; k < 8; ++k)
            s += __expf(v4[k].x - m) + __expf(v4[k].y - m)
               + __expf(v4[k].z - m) + __expf(v4[k].w - m);
        #pragma unroll
        for (int o = 32; o > 0; o >>= 1) s += __shfl_xor(s, o, 64);
        if (lane == 0) lse[row] = m + __logf(s);
    } else {
        // bucket build: one block per batch (LDS overlaid on sbuf)
        const int b = id - 1344;
        int* cnt = (int*)sbuf;          // 3000 ints
        int* part = cnt + VOC;          // 256 ints (13 KB total < 32 KB)
        const int* ceb = ce + (size_t)b * SRC;
        for (int v = tid; v < VOC; v += 256) cnt[v] = 0;
        __syncthreads();
        for (int s = tid; s < SRC; s += 256) atomicAdd(&cnt[ceb[s]], 1);
        __syncthreads();
        const int base = tid * 12;
        int lc[12];
        int tot = 0;
        #pragma unroll
        for (int k = 0; k < 12; ++k) {
            int v = base + k;
            lc[k] = (v < VOC) ? cnt[v] : 0;
            tot += lc[k];
        }
        part[tid] = tot;
        __syncthreads();
        for (int d = 1; d < 256; d <<= 1) {
            int val = (tid >= d) ? part[tid - d] : 0;
            __syncthreads();
            part[tid] += val;
            __syncthreads();
        }
        int run = part[tid] - tot;
        int* boffb = boff + b * 3008;
        #pragma unroll
        for (int k = 0; k < 12; ++k) {
            int v = base + k;
            if (v < VOC) { boffb[v] = run; cnt[v] = run; run += lc[k]; }
        }
        if (tid == 0) boffb[VOC] = SRC;
        __syncthreads();
        for (int s = tid; s < SRC; s += 256) {
            int idv = ceb[s];
            int jl = (s & 1) * 1024 + (s >> 1);
            int pos = atomicAdd(&cnt[idv], 1);
            bucket[(size_t)b * SRC + pos] = (u16)jl;
        }
    }
}

// ---------------- d4: atten — 512 blocks, XCD-grouped per (b,jj) ----------------
__global__ __launch_bounds__(256) void gemm_atten(
    const u16* __restrict__ memb, const u16* __restrict__ qkb,
    const int* __restrict__ ce, float* __restrict__ rowsum,
    u16* __restrict__ etb)
{
    __shared__ u16 As[2 * 4096];
    __shared__ u16 Bs[2 * 4096];
    const int i = blockIdx.x;
    const int xcd = i & 7, slot = i >> 3;        // slot in [0,64)
    const int bjj = xcd + 8 * (slot >> 4);       // [0,32) = b*2+jj
    const int inner = slot & 15;                 // 8 l-tiles x 2 t-tiles
    gemm_body<2, 512, NKE>((inner >> 1) * 128, (inner & 1) * 128, bjj,
                           memb, qkb, etb, ce, rowsum, As, Bs);
}

// ---------------- d5: combine-v6 — two-phase gather (entry-parallel loads -> LDS,
// then thread-per-v LDS-only reduce). 6144 blocks = 16 b x 32 tc x 12 vs. ----------------
__global__ __launch_bounds__(256) void combine(
    const u16* __restrict__ etb, const u16* __restrict__ bucket,
    const int* __restrict__ boff, const u16* __restrict__ qkb,
    const float* __restrict__ rowsum, const float* __restrict__ lse,
    const float* __restrict__ out_logits, float* __restrict__ out)
{
    __shared__ float part[CTILE][9];   // 9 KB entry partials (pad 9: conflict-free)
    __shared__ float acc[8][256];      // 8 KB [t-local][v-local]
    __shared__ float rcInv[8], rcGZ[8], rcEdl[8], rcDl[8];
    const int i = blockIdx.x;
    const int xcd = i & 7, slot = i >> 3;      // slot in [0,768)
    const int b = xcd + 8 * (slot / 384);      // all 384 blocks of b on one XCD
    const int inner = slot % 384;
    const int tc = inner / 12, vs = inner % 12;
    const int t0 = tc * 8;
    const int vbase = vs * 256;
    const int tid = threadIdx.x;
    const float EPSF = 1.1920929e-07f;

    if (tid < 8) {
        const int bt = b * TGT + t0 + tid;
        const float sent_v = bf2f(qkb[(size_t)bt * NKE + 512]) * SCALE;
        const float se = __expf(sent_v);
        const float sm = rowsum[bt] + se;
        const float inv = 1.0f / sm;
        const float g = sent_v - __logf(sm);
        const float eg = se * inv;
        const float dl = __logf(1.0f - eg + EPSF) - log1pf(-eg + EPSF);
        rcInv[tid] = inv;
        rcGZ[tid] = g - lse[bt];
        rcEdl[tid] = __expf(dl);
        rcDl[tid] = dl;
    }

    const int* boffb = boff + b * 3008;
    const u16* bukb = bucket + (size_t)b * SRC;
    const u16* etbb = etb + (size_t)b * SRC * TGT;

    const int vend = (vbase + 256 < VOC) ? vbase + 256 : VOC;
    const int e_lo = boffb[vbase];
    const int cnt = boffb[vend] - e_lo;
    const int v = vbase + tid;
    const int i0 = (v < VOC) ? boffb[v] - e_lo : 0;
    const int i1 = (v < VOC) ? boffb[v + 1] - e_lo : 0;

    float a[8] = {0.f, 0.f, 0.f, 0.f, 0.f, 0.f, 0.f, 0.f};
    for (int ts = 0; ts < cnt; ts += CTILE) {
        const int n = (cnt - ts < CTILE) ? cnt - ts : CTILE;
        __syncthreads();   // part[] free for reuse
        for (int e = tid; e < n; e += 256) {
            const int s = bukb[e_lo + ts + e];
            int4 u = *(const int4*)(etbb + (size_t)s * TGT + t0);
            part[e][0] = bf2f((u16)(u.x & 0xffff));
            part[e][1] = bf2f((u16)((unsigned)u.x >> 16));
            part[e][2] = bf2f((u16)(u.y & 0xffff));
            part[e][3] = bf2f((u16)((unsigned)u.y >> 16));
            part[e][4] = bf2f((u16)(u.z & 0xffff));
            part[e][5] = bf2f((u16)((unsigned)u.z >> 16));
            part[e][6] = bf2f((u16)(u.w & 0xffff));
            part[e][7] = bf2f((u16)((unsigned)u.w >> 16));
        }
        __syncthreads();
        int lo = i0 - ts; if (lo < 0) lo = 0;
        int hi = i1 - ts; if (hi > n) hi = n;
        for (int e = lo; e < hi; ++e) {
            #pragma unroll
            for (int k = 0; k < 8; ++k) a[k] += part[e][k];
        }
    }
    #pragma unroll
    for (int k = 0; k < 8; ++k) acc[k][tid] = a[k];
    __syncthreads();

    const int r = tid >> 5;
    const int vl0 = tid & 31;
    const int bt = b * TGT + t0 + r;
    const float inv = rcInv[r], gZ = rcGZ[r], edl = rcEdl[r], dlv = rcDl[r];
    const float* lrow = out_logits + (size_t)bt * TV;
    float* orow = out + (size_t)bt * VOC;
    #pragma unroll
    for (int kk = 0; kk < 8; ++kk) {
        const int vloc = vl0 + 32 * kk;
        const int vv = vbase + vloc;
        if (vv >= VOC) continue;
        float pv = acc[r][vloc] * inv + EPSF;
        float o;
        if (vv < TV) o = __logf(__expf(lrow[vv] + gZ) + pv * edl);
        else         o = __logf(pv) + dlv;
        orow[vv] = o;
    }
}

extern "C" void kernel_launch(void* const* d_in, const int* in_sizes, int n_in,
                              void* d_out, int out_size, void* d_ws, size_t ws_size,
                              hipStream_t stream) {
    const float* out_logits = (const float*)d_in[0];
    const float* feature    = (const float*)d_in[1];
    const float* memory_raw = (const float*)d_in[2];
    const int*   content_e  = (const int*)d_in[3];
    const float* Wq = (const float*)d_in[4];
    const float* bq = (const float*)d_in[5];
    const float* Wk = (const float*)d_in[6];
    const float* bk = (const float*)d_in[7];
    const float* sentinel = (const float*)d_in[8];
    float* out = (float*)d_out;

    u16* memb   = (u16*)d_ws;                             // 16384*512 bf16
    u16* featb  = memb   + (size_t)16384 * 512;           // 4096*512
    u16* wqT    = featb  + (size_t)4096 * 512;            // 512*512
    u16* wkE    = wqT    + (size_t)512 * 512;             // 1280*512
    u16* queryb = wkE    + (size_t)NKE * 512;             // 4096*512
    u16* qkb    = queryb + (size_t)4096 * 512;            // 4096*1280
    u16* etb    = qkb    + (size_t)4096 * NKE;            // 16*2048*256 bf16 E^T
    float* rowsum = (float*)(etb + (size_t)BSZ * SRC * TGT); // 4096 f32
    float* lse   = rowsum + 4096;                         // 4096 f32
    int* boff = (int*)(lse + 4096);                       // 16*3008 int
    u16* bucket = (u16*)(boff + 16 * 3008);               // 16*2048 u16

    prep_a<<<1601, 256, 0, stream>>>(feature, Wq, Wk, sentinel, bk,
                                     (int4*)featb, wqT, wkE, rowsum);
    k_query<<<4608, 256, 0, stream>>>(featb, wqT, bq, queryb, memory_raw, (int4*)memb);
    k_qk<<<1360, 256, 0, stream>>>(queryb, wkE, qkb, out_logits, lse,
                                   content_e, boff, bucket);
    gemm_atten<<<512, 256, 0, stream>>>(memb, qkb, content_e, rowsum, etb);
    combine<<<6144, 256, 0, stream>>>(etb, bucket, boff, qkb,
                                      rowsum, lse, out_logits, out);
}

// Round 21
// 89.481 us; speedup vs baseline: 1.0304x; 1.0020x over previous
//
#include <hip/hip_runtime.h>
#include <math.h>

#define BSZ   16
#define LSEQ  1024
#define TGT   256
#define HID   512
#define TV    2000
#define VOC   3000
#define SRC   2048
#define NKE   1280     // WkE rows: 2 j-halves x 640 (512 d + sentinel + bias + pad)
#define JOFF  640
#define CTILE 256      // combine entry tile
#define SCALE 0.044194173824159216f   // 1/sqrt(512)

typedef unsigned short u16;
typedef __attribute__((ext_vector_type(8))) short bf16x8;
typedef __attribute__((ext_vector_type(4))) float f32x4;

__device__ __forceinline__ u16 f2bf(float x) {
    unsigned u = __float_as_uint(x);
    u += 0x7FFFu + ((u >> 16) & 1u);
    return (u16)(u >> 16);
}
__device__ __forceinline__ float bf2f(u16 x) {
    return __uint_as_float((unsigned)x << 16);
}

static __device__ __forceinline__ float gelu_exact(float x) {
    return 0.5f * x * (1.0f + erff(x * 0.70710678118654752f));
}

// async 16B global -> LDS (wave-uniform LDS base + lane*16)
__device__ __forceinline__ void gload16(const u16* g, u16* l) {
    __builtin_amdgcn_global_load_lds(
        (const __attribute__((address_space(1))) unsigned int*)g,
        (__attribute__((address_space(3))) unsigned int*)l,
        16, 0, 0);
}

__device__ __forceinline__ void cast8_body(const float4* __restrict__ in,
                                           int4* __restrict__ out, int i) {
    float4 x = in[2 * i], y = in[2 * i + 1];
    unsigned p0 = (unsigned)f2bf(x.x) | ((unsigned)f2bf(x.y) << 16);
    unsigned p1 = (unsigned)f2bf(x.z) | ((unsigned)f2bf(x.w) << 16);
    unsigned p2 = (unsigned)f2bf(y.x) | ((unsigned)f2bf(y.y) << 16);
    unsigned p3 = (unsigned)f2bf(y.z) | ((unsigned)f2bf(y.w) << 16);
    out[i] = make_int4(p0, p1, p2, p3);
}

// ---------------- d1: prep_a — featb cast | Wq^T | WkE build | rowsum zero ----------------
// blocks: [0,1024) cast feature | [1024,1280) Wq^T | [1280,1600) WkE | 1600 rowsum=0
__global__ __launch_bounds__(256) void prep_a(
    const float* __restrict__ feature, const float* __restrict__ Wq,
    const float* __restrict__ Wk, const float* __restrict__ sentinel,
    const float* __restrict__ bk,
    int4* __restrict__ featb, u16* __restrict__ wqT, u16* __restrict__ wkE,
    float* __restrict__ rowsum)
{
    __shared__ float t[32][33];
    const int id = blockIdx.x;
    const int tid = threadIdx.x;
    if (id < 1024) {
        cast8_body((const float4*)feature, featb, id * 256 + tid);
    } else if (id < 1280) {
        int id2 = id - 1024;
        int bx = (id2 & 15) * 32, by = (id2 >> 4) * 32;
        const int tx = tid & 31, ty = tid >> 5;
        #pragma unroll
        for (int k = 0; k < 4; ++k)
            t[ty + 8 * k][tx] = Wq[(size_t)(by + ty + 8 * k) * 512 + bx + tx];
        __syncthreads();
        #pragma unroll
        for (int k = 0; k < 4; ++k)
            wqT[(size_t)(bx + ty + 8 * k) * 512 + by + tx] = f2bf(t[tx][ty + 8 * k]);
    } else if (id < 1600) {
        const int rr = (id - 1280) * 4 + (tid >> 6);   // 0..1279
        const int c = (tid & 63) * 8;
        const int j = rr >= JOFF;
        const int dd = rr - j * JOFF;
        u16* dst = wkE + (size_t)rr * HID + c;
        if (dd < 512) {
            const float* src = Wk + (size_t)dd * 1024 + j * 512 + c;
            #pragma unroll
            for (int k = 0; k < 8; ++k) dst[k] = f2bf(src[k]);
        } else if (dd == 512) {
            #pragma unroll
            for (int k = 0; k < 8; ++k) dst[k] = f2bf(sentinel[c + k]);
        } else if (dd == 513) {
            #pragma unroll
            for (int k = 0; k < 8; ++k) dst[k] = f2bf(bk[j * 512 + c + k]);
        } else {
            #pragma unroll
            for (int k = 0; k < 8; ++k) dst[k] = 0;
        }
    } else {
        float4* rz = (float4*)rowsum;
        for (int i = tid; i < 1024; i += 256) rz[i] = make_float4(0.f, 0.f, 0.f, 0.f);
    }
}

// ---------------- d2: query GEMM (512 blocks) + memb cast (4096 blocks) ----------------
__global__ __launch_bounds__(256) void k_query(
    const u16* __restrict__ feat, const u16* __restrict__ wqT,
    const float* __restrict__ bq, u16* __restrict__ queryb,
    const float* __restrict__ memory_raw, int4* __restrict__ memb)
{
    __shared__ u16 sbuf[2 * 2048 * 2];   // As | Bs (16 KB)
    const int id = blockIdx.x;
    const int tid = threadIdx.x;
    if (id >= 512) {
        cast8_body((const float4*)memory_raw, memb, (id - 512) * 256 + tid);
        return;
    }
    u16* As = sbuf;
    u16* Bs = sbuf + 2 * 2048;
    const int lane = tid & 63;
    const int w = tid >> 6;
    const int wr = (w >> 1) * 32, wc = (w & 1) * 32;
    const int m0 = (id >> 3) * 64, n0 = (id & 7) * 64;

    const int srow = tid >> 2, scol = (tid & 3) * 8;
    const u16* gA = feat + (size_t)(m0 + srow) * HID + scol;
    const u16* gB = wqT + (size_t)(n0 + srow) * HID + scol;

    const int la = lane & 15, lb = lane >> 4;
    f32x4 acc[2][2] = {};

    gload16(gA, As + w * 512);
    gload16(gB, Bs + w * 512);

    int cur = 0;
    for (int k0 = 0; k0 < HID; k0 += 32) {
        __syncthreads();   // drains vmcnt(0) + barrier
        const u16* Asb = As + cur * 2048;
        const u16* Bsb = Bs + cur * 2048;
        bf16x8 af[2], bf[2];
        #pragma unroll
        for (int i = 0; i < 2; ++i)
            af[i] = *(const bf16x8*)(Asb + (wr + i * 16 + la) * 32 + lb * 8);
        #pragma unroll
        for (int j = 0; j < 2; ++j)
            bf[j] = *(const bf16x8*)(Bsb + (wc + j * 16 + la) * 32 + lb * 8);
        if (k0 + 32 < HID) {
            const int nb = cur ^ 1;
            gload16(gA + k0 + 32, As + nb * 2048 + w * 512);
            gload16(gB + k0 + 32, Bs + nb * 2048 + w * 512);
        }
        #pragma unroll
        for (int i = 0; i < 2; ++i)
            #pragma unroll
            for (int j = 0; j < 2; ++j)
                acc[i][j] = __builtin_amdgcn_mfma_f32_16x16x32_bf16(af[i], bf[j], acc[i][j], 0, 0, 0);
        cur ^= 1;
    }

    const int r_l = (lane >> 4) * 4, c_l = lane & 15;
    #pragma unroll
    for (int j = 0; j < 2; ++j) {
        const int n = n0 + wc + j * 16 + c_l;
        const float bv = bq[n];
        #pragma unroll
        for (int i = 0; i < 2; ++i)
            #pragma unroll
            for (int r = 0; r < 4; ++r) {
                const int m = m0 + wr + i * 16 + r_l + r;
                queryb[(size_t)m * HID + n] = f2bf(gelu_exact(acc[i][j][r] + bv));
            }
    }
}

// ---------------- MFMA GEMM body (128x128, BK=32) for qk ----------------
template<int EPI, int LDA, int LDB>
__device__ __forceinline__ void gemm_body(
    int m0, int n0, int z,
    const u16* __restrict__ Abase, const u16* __restrict__ Bbase,
    u16* __restrict__ outb,
    const int* __restrict__ ce, float* __restrict__ rowsum,
    u16* __restrict__ As, u16* __restrict__ Bs)   // each 2*4096 u16
{
    const int tid = threadIdx.x;
    const int lane = tid & 63;
    const int w = tid >> 6;
    const int wr = (w >> 1) * 64, wc = (w & 1) * 64;

    const u16* Ag = Abase;
    const u16* Bg = Bbase;

    const int chunkrow = lane >> 2;
    const int colc = (lane & 3) * 8;
    const int c0 = w * 2, c1 = c0 + 1;
    const u16* gA0 = Ag + (size_t)(m0 + c0 * 16 + chunkrow) * LDA + colc;
    const u16* gA1 = Ag + (size_t)(m0 + c1 * 16 + chunkrow) * LDA + colc;
    const u16* gB0 = Bg + (size_t)(n0 + c0 * 16 + chunkrow) * LDB + colc;
    const u16* gB1 = Bg + (size_t)(n0 + c1 * 16 + chunkrow) * LDB + colc;

    const int la = lane & 15, lb = lane >> 4;
    f32x4 acc[4][4] = {};

    gload16(gA0, As + c0 * 512);
    gload16(gA1, As + c1 * 512);
    gload16(gB0, Bs + c0 * 512);
    gload16(gB1, Bs + c1 * 512);

    int cur = 0;
    for (int k0 = 0; k0 < HID; k0 += 32) {
        __syncthreads();
        const u16* Asb = As + cur * 4096;
        const u16* Bsb = Bs + cur * 4096;
        bf16x8 af[4], bfv[4];
        #pragma unroll
        for (int i = 0; i < 4; ++i)
            af[i] = *(const bf16x8*)(Asb + (wr + i * 16 + la) * 32 + lb * 8);
        #pragma unroll
        for (int j = 0; j < 4; ++j)
            bfv[j] = *(const bf16x8*)(Bsb + (wc + j * 16 + la) * 32 + lb * 8);
        if (k0 + 32 < HID) {
            const int nb = cur ^ 1;
            u16* An = As + nb * 4096;
            u16* Bn = Bs + nb * 4096;
            gload16(gA0 + k0 + 32, An + c0 * 512);
            gload16(gA1 + k0 + 32, An + c1 * 512);
            gload16(gB0 + k0 + 32, Bn + c0 * 512);
            gload16(gB1 + k0 + 32, Bn + c1 * 512);
        }
        #pragma unroll
        for (int i = 0; i < 4; ++i)
            #pragma unroll
            for (int j = 0; j < 4; ++j)
                acc[i][j] = __builtin_amdgcn_mfma_f32_16x16x32_bf16(af[i], bfv[j], acc[i][j], 0, 0, 0);
        cur ^= 1;
    }

    const int r_l = (lane >> 4) * 4, c_l = lane & 15;
    #pragma unroll
    for (int j = 0; j < 4; ++j) {
        const int n = n0 + wc + j * 16 + c_l;
        #pragma unroll
        for (int i = 0; i < 4; ++i)
            #pragma unroll
            for (int r = 0; r < 4; ++r) {
                const int m = m0 + wr + i * 16 + r_l + r;
                outb[(size_t)m * NKE + n] = f2bf(acc[i][j][r]);
            }
    }
}

// ---------------- d3: qk GEMM (320) + logits LSE (1024) + bucket build (16) ----------------
__global__ __launch_bounds__(256) void k_qk(
    const u16* __restrict__ queryb, const u16* __restrict__ wkE,
    u16* __restrict__ qkb,
    const float* __restrict__ logits, float* __restrict__ lse,
    const int* __restrict__ ce, int* __restrict__ boff, u16* __restrict__ bucket)
{
    __shared__ u16 sbuf[4 * 4096];   // 32 KB: GEMM As|Bs, or bucket cnt|part overlay
    const int id = blockIdx.x;
    const int tid = threadIdx.x;
    if (id < 320) {
        gemm_body<3, 512, 512>((id / 10) * 128, (id % 10) * 128, 0,
                               queryb, wkE, qkb, nullptr, nullptr,
                               sbuf, sbuf + 2 * 4096);
    } else if (id < 1344) {
        // logits LSE: 4 rows per block, one wave per row (TV = 500 float4)
        const int row = (id - 320) * 4 + (tid >> 6);
        const int lane = tid & 63;
        const float4* lrow4 = (const float4*)(logits + (size_t)row * TV);
        float4 v4[8];
        float m = -INFINITY;
        #pragma unroll
        for (int k = 0; k < 8; ++k) {
            int idx = lane + 64 * k;
            if (idx < 500) {
                v4[k] = lrow4[idx];
                m = fmaxf(m, fmaxf(fmaxf(v4[k].x, v4[k].y), fmaxf(v4[k].z, v4[k].w)));
            } else {
                v4[k] = make_float4(-INFINITY, -INFINITY, -INFINITY, -INFINITY);
            }
        }
        #pragma unroll
        for (int o = 32; o > 0; o >>= 1) m = fmaxf(m, __shfl_xor(m, o, 64));
        float s = 0.f;
        #pragma unroll
        for (int k = 0; k < 8; ++k)
            s += __expf(v4[k].x - m) + __expf(v4[k].y - m)
               + __expf(v4[k].z - m) + __expf(v4[k].w - m);
        #pragma unroll
        for (int o = 32; o > 0; o >>= 1) s += __shfl_xor(s, o, 64);
        if (lane == 0) lse[row] = m + __logf(s);
    } else {
        // bucket build: one block per batch (LDS overlaid on sbuf)
        const int b = id - 1344;
        int* cnt = (int*)sbuf;          // 3000 ints
        int* part = cnt + VOC;          // 256 ints (13 KB total < 32 KB)
        const int* ceb = ce + (size_t)b * SRC;
        for (int v = tid; v < VOC; v += 256) cnt[v] = 0;
        __syncthreads();
        for (int s = tid; s < SRC; s += 256) atomicAdd(&cnt[ceb[s]], 1);
        __syncthreads();
        const int base = tid * 12;
        int lc[12];
        int tot = 0;
        #pragma unroll
        for (int k = 0; k < 12; ++k) {
            int v = base + k;
            lc[k] = (v < VOC) ? cnt[v] : 0;
            tot += lc[k];
        }
        part[tid] = tot;
        __syncthreads();
        for (int d = 1; d < 256; d <<= 1) {
            int val = (tid >= d) ? part[tid - d] : 0;
            __syncthreads();
            part[tid] += val;
            __syncthreads();
        }
        int run = part[tid] - tot;
        int* boffb = boff + b * 3008;
        #pragma unroll
        for (int k = 0; k < 12; ++k) {
            int v = base + k;
            if (v < VOC) { boffb[v] = run; cnt[v] = run; run += lc[k]; }
        }
        if (tid == 0) boffb[VOC] = SRC;
        __syncthreads();
        for (int s = tid; s < SRC; s += 256) {
            int idv = ceb[s];
            int jl = (s & 1) * 1024 + (s >> 1);
            int pos = atomicAdd(&cnt[idv], 1);
            bucket[(size_t)b * SRC + pos] = (u16)jl;
        }
    }
}

// ---------------- d4: atten — 1024 blocks (128x64 tiles), XCD-grouped per (b,jj) ----------------
__global__ __launch_bounds__(256) void k_atten(
    const u16* __restrict__ memb, const u16* __restrict__ qkb,
    const int* __restrict__ ce, float* __restrict__ rowsum,
    u16* __restrict__ etb)
{
    __shared__ u16 As[2 * 4096];   // 128x32 dbuf (16 KB)
    __shared__ u16 Bs[2 * 2048];   // 64x32 dbuf (8 KB)
    const int i = blockIdx.x;
    const int xcd = i & 7, slot = i >> 3;        // slot in [0,128)
    const int bjj = xcd + 8 * (slot >> 5);       // [0,32) = b*2+jj
    const int inner = slot & 31;                 // 8 l-tiles x 4 t-tiles
    const int m0 = (inner >> 2) * 128;           // l
    const int n0 = (inner & 3) * 64;             // t
    const int b = bjj >> 1, jj = bjj & 1;

    const int tid = threadIdx.x;
    const int lane = tid & 63;
    const int w = tid >> 6;
    const int wr = (w >> 1) * 64, wc = (w & 1) * 32;

    const u16* Ag = memb + (size_t)b * LSEQ * HID;
    const u16* Bg = qkb + (size_t)b * TGT * NKE + (size_t)jj * JOFF;

    const int chunkrow = lane >> 2;
    const int colc = (lane & 3) * 8;
    const int c0 = w * 2, c1 = c0 + 1;
    const u16* gA0 = Ag + (size_t)(m0 + c0 * 16 + chunkrow) * HID + colc;
    const u16* gA1 = Ag + (size_t)(m0 + c1 * 16 + chunkrow) * HID + colc;
    const u16* gB  = Bg + (size_t)(n0 + w * 16 + chunkrow) * NKE + colc;

    const int la = lane & 15, lb = lane >> 4;
    f32x4 acc[4][2] = {};

    gload16(gA0, As + c0 * 512);
    gload16(gA1, As + c1 * 512);
    gload16(gB,  Bs + w * 512);

    int cur = 0;
    for (int k0 = 0; k0 < HID; k0 += 32) {
        __syncthreads();   // drains vmcnt(0) (stage complete) + barrier
        const u16* Asb = As + cur * 4096;
        const u16* Bsb = Bs + cur * 2048;
        bf16x8 af[4], bfv[2];
        #pragma unroll
        for (int ii = 0; ii < 4; ++ii)
            af[ii] = *(const bf16x8*)(Asb + (wr + ii * 16 + la) * 32 + lb * 8);
        #pragma unroll
        for (int j = 0; j < 2; ++j)
            bfv[j] = *(const bf16x8*)(Bsb + (wc + j * 16 + la) * 32 + lb * 8);
        if (k0 + 32 < HID) {
            const int nb = cur ^ 1;
            gload16(gA0 + k0 + 32, As + nb * 4096 + c0 * 512);
            gload16(gA1 + k0 + 32, As + nb * 4096 + c1 * 512);
            gload16(gB + k0 + 32,  Bs + nb * 2048 + w * 512);
        }
        #pragma unroll
        for (int ii = 0; ii < 4; ++ii)
            #pragma unroll
            for (int j = 0; j < 2; ++j)
                acc[ii][j] = __builtin_amdgcn_mfma_f32_16x16x32_bf16(af[ii], bfv[j], acc[ii][j], 0, 0, 0);
        cur ^= 1;
    }

    // epilogue: exp + mask + store E^T + column(t) partial sums
    const int r_l = (lane >> 4) * 4, c_l = lane & 15;
    float biasc[2];
    #pragma unroll
    for (int j = 0; j < 2; ++j) {
        const int n = n0 + wc + j * 16 + c_l;   // t
        biasc[j] = bf2f(qkb[(size_t)(b * TGT + n) * NKE + jj * JOFF + 513]);
    }
    const int* ceb = ce + (size_t)b * SRC;
    float csum[2] = {0.f, 0.f};
    #pragma unroll
    for (int ii = 0; ii < 4; ++ii)
        #pragma unroll
        for (int r = 0; r < 4; ++r) {
            const int m = m0 + wr + ii * 16 + r_l + r;      // l
            const int cm = ceb[2 * m + jj];
            const size_t rowbase = ((size_t)b * SRC + jj * 1024 + m) * TGT;
            #pragma unroll
            for (int j = 0; j < 2; ++j) {
                float ev = (cm == 0) ? 0.f
                         : __expf((acc[ii][j][r] + biasc[j]) * SCALE);
                etb[rowbase + n0 + wc + j * 16 + c_l] = f2bf(ev);
                csum[j] += ev;
            }
        }
    #pragma unroll
    for (int j = 0; j < 2; ++j) {
        csum[j] += __shfl_xor(csum[j], 16, 64);
        csum[j] += __shfl_xor(csum[j], 32, 64);
    }
    const int g4 = lane >> 4;
    if (g4 < 2) {
        float myv = (g4 == 0) ? csum[0] : csum[1];
        atomicAdd(&rowsum[b * TGT + n0 + wc + g4 * 16 + c_l], myv);
    }
}

// ---------------- d5: combine-v6 — two-phase gather. 6144 blocks = 16 b x 32 tc x 12 vs ----------------
__global__ __launch_bounds__(256) void combine(
    const u16* __restrict__ etb, const u16* __restrict__ bucket,
    const int* __restrict__ boff, const u16* __restrict__ qkb,
    const float* __restrict__ rowsum, const float* __restrict__ lse,
    const float* __restrict__ out_logits, float* __restrict__ out)
{
    __shared__ float part[CTILE][9];   // 9 KB entry partials (pad 9: conflict-free)
    __shared__ float acc[8][256];      // 8 KB [t-local][v-local]
    __shared__ float rcInv[8], rcGZ[8], rcEdl[8], rcDl[8];
    const int i = blockIdx.x;
    const int xcd = i & 7, slot = i >> 3;      // slot in [0,768)
    const int b = xcd + 8 * (slot / 384);      // all 384 blocks of b on one XCD
    const int inner = slot % 384;
    const int tc = inner / 12, vs = inner % 12;
    const int t0 = tc * 8;
    const int vbase = vs * 256;
    const int tid = threadIdx.x;
    const float EPSF = 1.1920929e-07f;

    if (tid < 8) {
        const int bt = b * TGT + t0 + tid;
        const float sent_v = bf2f(qkb[(size_t)bt * NKE + 512]) * SCALE;
        const float se = __expf(sent_v);
        const float sm = rowsum[bt] + se;
        const float inv = 1.0f / sm;
        const float g = sent_v - __logf(sm);
        const float eg = se * inv;
        const float dl = __logf(1.0f - eg + EPSF) - log1pf(-eg + EPSF);
        rcInv[tid] = inv;
        rcGZ[tid] = g - lse[bt];
        rcEdl[tid] = __expf(dl);
        rcDl[tid] = dl;
    }

    const int* boffb = boff + b * 3008;
    const u16* bukb = bucket + (size_t)b * SRC;
    const u16* etbb = etb + (size_t)b * SRC * TGT;

    const int vend = (vbase + 256 < VOC) ? vbase + 256 : VOC;
    const int e_lo = boffb[vbase];
    const int cnt = boffb[vend] - e_lo;
    const int v = vbase + tid;
    const int i0 = (v < VOC) ? boffb[v] - e_lo : 0;
    const int i1 = (v < VOC) ? boffb[v + 1] - e_lo : 0;

    float a[8] = {0.f, 0.f, 0.f, 0.f, 0.f, 0.f, 0.f, 0.f};
    for (int ts = 0; ts < cnt; ts += CTILE) {
        const int n = (cnt - ts < CTILE) ? cnt - ts : CTILE;
        __syncthreads();   // part[] free for reuse
        for (int e = tid; e < n; e += 256) {
            const int s = bukb[e_lo + ts + e];
            int4 u = *(const int4*)(etbb + (size_t)s * TGT + t0);
            part[e][0] = bf2f((u16)(u.x & 0xffff));
            part[e][1] = bf2f((u16)((unsigned)u.x >> 16));
            part[e][2] = bf2f((u16)(u.y & 0xffff));
            part[e][3] = bf2f((u16)((unsigned)u.y >> 16));
            part[e][4] = bf2f((u16)(u.z & 0xffff));
            part[e][5] = bf2f((u16)((unsigned)u.z >> 16));
            part[e][6] = bf2f((u16)(u.w & 0xffff));
            part[e][7] = bf2f((u16)((unsigned)u.w >> 16));
        }
        __syncthreads();
        int lo = i0 - ts; if (lo < 0) lo = 0;
        int hi = i1 - ts; if (hi > n) hi = n;
        for (int e = lo; e < hi; ++e) {
            #pragma unroll
            for (int k = 0; k < 8; ++k) a[k] += part[e][k];
        }
    }
    #pragma unroll
    for (int k = 0; k < 8; ++k) acc[k][tid] = a[k];
    __syncthreads();

    const int r = tid >> 5;
    const int vl0 = tid & 31;
    const int bt = b * TGT + t0 + r;
    const float inv = rcInv[r], gZ = rcGZ[r], edl = rcEdl[r], dlv = rcDl[r];
    const float* lrow = out_logits + (size_t)bt * TV;
    float* orow = out + (size_t)bt * VOC;
    #pragma unroll
    for (int kk = 0; kk < 8; ++kk) {
        const int vloc = vl0 + 32 * kk;
        const int vv = vbase + vloc;
        if (vv >= VOC) continue;
        float pv = acc[r][vloc] * inv + EPSF;
        float o;
        if (vv < TV) o = __logf(__expf(lrow[vv] + gZ) + pv * edl);
        else         o = __logf(pv) + dlv;
        orow[vv] = o;
    }
}

extern "C" void kernel_launch(void* const* d_in, const int* in_sizes, int n_in,
                              void* d_out, int out_size, void* d_ws, size_t ws_size,
                              hipStream_t stream) {
    const float* out_logits = (const float*)d_in[0];
    const float* feature    = (const float*)d_in[1];
    const float* memory_raw = (const float*)d_in[2];
    const int*   content_e  = (const int*)d_in[3];
    const float* Wq = (const float*)d_in[4];
    const float* bq = (const float*)d_in[5];
    const float* Wk = (const float*)d_in[6];
    const float* bk = (const float*)d_in[7];
    const float* sentinel = (const float*)d_in[8];
    float* out = (float*)d_out;

    u16* memb   = (u16*)d_ws;                             // 16384*512 bf16
    u16* featb  = memb   + (size_t)16384 * 512;           // 4096*512
    u16* wqT    = featb  + (size_t)4096 * 512;            // 512*512
    u16* wkE    = wqT    + (size_t)512 * 512;             // 1280*512
    u16* queryb = wkE    + (size_t)NKE * 512;             // 4096*512
    u16* qkb    = queryb + (size_t)4096 * 512;            // 4096*1280
    u16* etb    = qkb    + (size_t)4096 * NKE;            // 16*2048*256 bf16 E^T
    float* rowsum = (float*)(etb + (size_t)BSZ * SRC * TGT); // 4096 f32
    float* lse   = rowsum + 4096;                         // 4096 f32
    int* boff = (int*)(lse + 4096);                       // 16*3008 int
    u16* bucket = (u16*)(boff + 16 * 3008);               // 16*2048 u16

    prep_a<<<1601, 256, 0, stream>>>(feature, Wq, Wk, sentinel, bk,
                                     (int4*)featb, wqT, wkE, rowsum);
    k_query<<<4608, 256, 0, stream>>>(featb, wqT, bq, queryb, memory_raw, (int4*)memb);
    k_qk<<<1360, 256, 0, stream>>>(queryb, wkE, qkb, out_logits, lse,
                                   content_e, boff, bucket);
    k_atten<<<1024, 256, 0, stream>>>(memb, qkb, content_e, rowsum, etb);
    combine<<<6144, 256, 0, stream>>>(etb, bucket, boff, qkb,
                                      rowsum, lse, out_logits, out);
}